// Round 10
// baseline (187.188 us; speedup 1.0000x reference)
//
#include <hip/hip_runtime.h>
#include <hip/hip_bf16.h>

#define N_NODES 50000
#define N_EDGES 800000
#define D_IN    1024
#define D_OUT   256
#define CAP     64
#define LEAKY   0.01f

typedef __attribute__((ext_vector_type(8))) short bf16x8;
typedef __attribute__((ext_vector_type(4))) float f32x4;
typedef __attribute__((ext_vector_type(4))) int   i32x4;
typedef unsigned short u16;

__device__ __forceinline__ u16 f2bfu(float f) {
  uint32_t x = __float_as_uint(f);
  uint32_t r = (x + 0x7FFFu + ((x >> 16) & 1u)) >> 16;  // RNE
  return (u16)r;
}
__device__ __forceinline__ float bfu2f(u16 u) {
  return __uint_as_float(((uint32_t)u) << 16);
}
// XOR swizzle on a 128-B stripe: flip byte bits 4-6 with stripe-row low bits.
__device__ __forceinline__ int swz(int b) { return b ^ (((b >> 7) & 7) << 4); }
// Tile address for [row r][byte col c<64] with 64-B rows, paired into 128-B
// stripes: 16 rows reading one col -> 8 distinct 16-B slots x 2 = conflict-free.
__device__ __forceinline__ int paddr(int r, int c) {
  return swz(((r) >> 1) * 128 + ((r) & 1) * 64 + (c));
}

__device__ __forceinline__ void gll16(const void* g, void* l) {
  __builtin_amdgcn_global_load_lds(
      (const __attribute__((address_space(1))) uint32_t*)g,
      (__attribute__((address_space(3))) uint32_t*)l, 16, 0, 0);
}

// ---------------------------------------------------------------------------
// Kernel 1: weight fp32 [1024][256] -> bf16 image of 32 k-tiles, each a
// [256 n][32 k] paddr-swizzled 16-KB block (gll'd linearly by the GEMM).
// Also zeroes deg[]. Reads coalesced (consecutive t -> consecutive n).
// ---------------------------------------------------------------------------
__global__ __launch_bounds__(256) void wconv_kernel(const float* __restrict__ w,
                                                    char* __restrict__ img,
                                                    int* __restrict__ deg) {
  const int t = blockIdx.x * 256 + threadIdx.x;   // 0..32767
  if (t < N_NODES) deg[t] = 0;
  const int t2 = t + 32768;
  if (t2 < N_NODES) deg[t2] = 0;

  const int n   = t & 255;
  const int kc  = (t >> 8) * 8;     // 8-wide k chunk
  const int kt  = kc >> 5;          // k-tile 0..31
  const int kin = kc & 31;          // 0,8,16,24
  bf16x8 v;
#pragma unroll
  for (int i = 0; i < 8; ++i) v[i] = (short)f2bfu(w[(size_t)(kc + i) * D_OUT + n]);
  *(bf16x8*)(img + kt * 16384 + paddr(n, kin * 2)) = v;
}

// ---------------------------------------------------------------------------
// Kernel 2 (FUSED): 60 build blocks + 196 GEMM blocks = 256 = one per CU,
// SINGLE ROUND. GEMM: BM=256 (W image read by 196 blocks instead of 782:
// W traffic 433->100 MB; total memory demand ~300 MB vs 650).
// BK=32, 3-slot W (gll, staged 2 ahead) + 3-slot X LDS (96 KB total).
// Counted vmcnt(6) sync -- never drains; ~1.7 phases of gll slack, ~1 phase
// x-load slack. 8 waves = 4m x 2n, wave tile 64m x 128n, acc[8][4].
// ---------------------------------------------------------------------------
#define BMg 256
#define GEMM_BLOCKS ((N_NODES + BMg - 1) / BMg)   // 196
#define BUILD_BLOCKS 60                            // 60 + 196 = 256

__global__ __launch_bounds__(512) void gemm_build_kernel(
    const float* __restrict__ x, const char* __restrict__ img,
    u16* __restrict__ support,
    const int* __restrict__ ei, const float* __restrict__ ew,
    int* __restrict__ deg, int2* __restrict__ csr) {
  __shared__ u16 Wbuf[3][8192];   // 3 x 16 KB  [256 n][32 k] swizzled
  __shared__ u16 Xbuf[3][8192];   // 3 x 16 KB  [256 m][32 k] swizzled

  if (blockIdx.x < BUILD_BLOCKS) {
    const int t0 = blockIdx.x * 512 + threadIdx.x;
    for (int e = t0; e < N_EDGES; e += BUILD_BLOCKS * 512) {
      const int src = ei[e];
      const int dst = ei[N_EDGES + e];
      const float w = ew[e];
      const int slot = atomicAdd(&deg[dst], 1);
      if (slot < CAP) csr[dst * CAP + slot] = make_int2(src, __float_as_int(w));
    }
    return;
  }

  const int tid  = threadIdx.x;
  const int lane = tid & 63;
  const int wid  = tid >> 6;
  const int wn   = wid & 1;    // n-half (128 cols)
  const int wm   = wid >> 1;   // m-quarter (64 rows)
  const int l15  = lane & 15;
  const int l16  = lane >> 4;
  const int m0   = (blockIdx.x - BUILD_BLOCKS) * BMg;

  f32x4 acc[8][4];
#pragma unroll
  for (int i = 0; i < 8; ++i)
#pragma unroll
    for (int j = 0; j < 4; ++j) acc[i][j] = (f32x4)0.0f;

  // x staging: thread -> (row = tid>>1, 16-float k-chunk (tid&1)).
  const int xrow = tid >> 1;                 // 0..255
  const int xkc  = (tid & 1) * 16;           // float offset in k-tile
  const int xrg  = min(m0 + xrow, N_NODES - 1);
  const float* xp = x + (size_t)xrg * D_IN + xkc;
  const int xw0 = paddr(xrow, xkc * 2);
  const int xw1 = paddr(xrow, xkc * 2 + 16);

  // fragment byte offsets (constant across tiles)
  int a_off[8], b_off[4];
#pragma unroll
  for (int nf = 0; nf < 8; ++nf)
    a_off[nf] = paddr(wn * 128 + nf * 16 + l15, l16 * 16);
#pragma unroll
  for (int mf = 0; mf < 4; ++mf)
    b_off[mf] = paddr(wm * 64 + mf * 16 + l15, l16 * 16);

  f32x4 xr[2][4];   // 2 rotating x reg sets (ext-vector: nontemporal-legal)

#define XLOAD(set, tile) do {                                              \
    const int kcl_ = min((tile), 31);                                      \
    const float* p_ = xp + kcl_ * 32;                                      \
    xr[set][0] = __builtin_nontemporal_load((const f32x4*)(p_));           \
    xr[set][1] = __builtin_nontemporal_load((const f32x4*)(p_ + 4));       \
    xr[set][2] = __builtin_nontemporal_load((const f32x4*)(p_ + 8));       \
    xr[set][3] = __builtin_nontemporal_load((const f32x4*)(p_ + 12));      \
  } while (0)

#define GLL(sl, tile) do {                                                 \
    const int kcl_ = min((tile), 31);                                      \
    gll16(img + kcl_ * 16384 + tid * 16, (char*)&Wbuf[sl][0] + tid * 16);  \
    gll16(img + kcl_ * 16384 + 8192 + tid * 16,                            \
          (char*)&Wbuf[sl][0] + 8192 + tid * 16);                          \
  } while (0)

#define XCVT(set, sl) do {                                                 \
    bf16x8 v0_, v1_;                                                       \
    v0_[0] = (short)f2bfu(xr[set][0][0]); v0_[1] = (short)f2bfu(xr[set][0][1]); \
    v0_[2] = (short)f2bfu(xr[set][0][2]); v0_[3] = (short)f2bfu(xr[set][0][3]); \
    v0_[4] = (short)f2bfu(xr[set][1][0]); v0_[5] = (short)f2bfu(xr[set][1][1]); \
    v0_[6] = (short)f2bfu(xr[set][1][2]); v0_[7] = (short)f2bfu(xr[set][1][3]); \
    v1_[0] = (short)f2bfu(xr[set][2][0]); v1_[1] = (short)f2bfu(xr[set][2][1]); \
    v1_[2] = (short)f2bfu(xr[set][2][2]); v1_[3] = (short)f2bfu(xr[set][2][3]); \
    v1_[4] = (short)f2bfu(xr[set][3][0]); v1_[5] = (short)f2bfu(xr[set][3][1]); \
    v1_[6] = (short)f2bfu(xr[set][3][2]); v1_[7] = (short)f2bfu(xr[set][3][3]); \
    *(bf16x8*)((char*)&Xbuf[sl][0] + xw0) = v0_;                           \
    *(bf16x8*)((char*)&Xbuf[sl][0] + xw1) = v1_;                           \
  } while (0)

#define MFMA_TILE(sl) do {                                                 \
    bf16x8 af_[8], bf_[4];                                                 \
    _Pragma("unroll")                                                      \
    for (int nf_ = 0; nf_ < 8; ++nf_)                                      \
      af_[nf_] = *(const bf16x8*)((const char*)&Wbuf[sl][0] + a_off[nf_]); \
    _Pragma("unroll")                                                      \
    for (int mf_ = 0; mf_ < 4; ++mf_)                                      \
      bf_[mf_] = *(const bf16x8*)((const char*)&Xbuf[sl][0] + b_off[mf_]); \
    _Pragma("unroll")                                                      \
    for (int nf_ = 0; nf_ < 8; ++nf_)                                      \
      _Pragma("unroll")                                                    \
      for (int mf_ = 0; mf_ < 4; ++mf_)                                    \
        acc[nf_][mf_] = __builtin_amdgcn_mfma_f32_16x16x32_bf16(           \
            af_[nf_], bf_[mf_], acc[nf_][mf_], 0, 0, 0);                   \
  } while (0)

#define SYNC() do {                                                        \
    asm volatile("s_waitcnt vmcnt(6)" ::: "memory");                       \
    __builtin_amdgcn_sched_barrier(0);                                     \
    asm volatile("s_waitcnt lgkmcnt(0)" ::: "memory");                     \
    __builtin_amdgcn_s_barrier();                                          \
  } while (0)

  // BODY(iter i): compute tile i (slot sA), write x(i+1) into slot sB,
  // load x(i+2) into set eN, gll W(i+2) into slot sC, counted sync.
#define BODY(sA, sB, sC, eN, eC, kt) do {                                  \
    MFMA_TILE(sA);                                                         \
    XCVT(eC, sB);                                                          \
    XLOAD(eN, (kt) + 2);                                                   \
    GLL(sC, (kt) + 2);                                                     \
    SYNC();                                                                \
  } while (0)

  // ---- prologue: tiles 0,1 staged; Xbuf[0] written; gll(0) drained ----
  XLOAD(0, 0);
  GLL(0, 0);
  XLOAD(1, 1);
  GLL(1, 1);
  XCVT(0, 0);                                   // auto-waits x(0)
  asm volatile("s_waitcnt vmcnt(6)" ::: "memory");   // gll(0) done
  __builtin_amdgcn_sched_barrier(0);
  asm volatile("s_waitcnt lgkmcnt(0)" ::: "memory");
  __builtin_amdgcn_s_barrier();

  // ---- 32 iterations: 5 x 6-unroll + 2 tail ----
  for (int kt = 0; kt < 30; kt += 6) {
    BODY(0, 1, 2, 0, 1, kt);
    BODY(1, 2, 0, 1, 0, kt + 1);
    BODY(2, 0, 1, 0, 1, kt + 2);
    BODY(0, 1, 2, 1, 0, kt + 3);
    BODY(1, 2, 0, 0, 1, kt + 4);
    BODY(2, 0, 1, 1, 0, kt + 5);
  }
  BODY(0, 1, 2, 0, 1, 30);
  BODY(1, 2, 0, 1, 0, 31);

#undef XLOAD
#undef GLL
#undef XCVT
#undef MFMA_TILE
#undef SYNC
#undef BODY

  // D: m = m0 + wm*64 + mf*16 + l15, n = wn*128 + nf*16 + l16*4 + reg.
#pragma unroll
  for (int mf = 0; mf < 4; ++mf) {
    const int m = m0 + wm * 64 + mf * 16 + l15;
    if (m < N_NODES) {
#pragma unroll
      for (int nf = 0; nf < 8; ++nf) {
        const int n = wn * 128 + nf * 16 + l16 * 4;
        ushort4 o;
        o.x = f2bfu(acc[nf][mf][0]);
        o.y = f2bfu(acc[nf][mf][1]);
        o.z = f2bfu(acc[nf][mf][2]);
        o.w = f2bfu(acc[nf][mf][3]);
        *(ushort4*)&support[(size_t)m * D_OUT + n] = o;
      }
    }
  }
}

// ---------------------------------------------------------------------------
// Kernel 3: per-node gather-aggregate + epilogue (r5/r8 version, ~20 us).
// ---------------------------------------------------------------------------
__global__ __launch_bounds__(256) void agg_kernel(const u16* __restrict__ support,
                                                  const int* __restrict__ deg,
                                                  const int2* __restrict__ csr,
                                                  const float* __restrict__ norm,
                                                  const float* __restrict__ bias,
                                                  float* __restrict__ out) {
  const int lane = threadIdx.x & 63;
  const int wid  = threadIdx.x >> 6;
  const int node = blockIdx.x * 4 + wid;   // grid 12500 -> exactly 50000
  const int d    = min(deg[node], CAP);
  const int cb   = node * CAP;
  const int ch   = lane * 4;

  float a0 = 0.f, a1 = 0.f, a2 = 0.f, a3 = 0.f;
  int s = 0;

  for (; s + 16 <= d; s += 16) {
    i32x4 q[8];
#pragma unroll
    for (int i = 0; i < 8; ++i)
      q[i] = __builtin_nontemporal_load((const i32x4*)&csr[cb + s + 2 * i]);
    ushort4 v[16];
#pragma unroll
    for (int i = 0; i < 8; ++i) {
      v[2 * i]     = *(const ushort4*)&support[(size_t)q[i][0] * D_OUT + ch];
      v[2 * i + 1] = *(const ushort4*)&support[(size_t)q[i][2] * D_OUT + ch];
    }
#pragma unroll
    for (int i = 0; i < 8; ++i) {
      const float wa = __int_as_float(q[i][1]);
      const float wb = __int_as_float(q[i][3]);
      a0 = fmaf(wa, bfu2f(v[2 * i].x), a0);
      a1 = fmaf(wa, bfu2f(v[2 * i].y), a1);
      a2 = fmaf(wa, bfu2f(v[2 * i].z), a2);
      a3 = fmaf(wa, bfu2f(v[2 * i].w), a3);
      a0 = fmaf(wb, bfu2f(v[2 * i + 1].x), a0);
      a1 = fmaf(wb, bfu2f(v[2 * i + 1].y), a1);
      a2 = fmaf(wb, bfu2f(v[2 * i + 1].z), a2);
      a3 = fmaf(wb, bfu2f(v[2 * i + 1].w), a3);
    }
  }

  for (; s + 8 <= d; s += 8) {
    i32x4 q[4];
#pragma unroll
    for (int i = 0; i < 4; ++i)
      q[i] = __builtin_nontemporal_load((const i32x4*)&csr[cb + s + 2 * i]);
    ushort4 v[8];
#pragma unroll
    for (int i = 0; i < 4; ++i) {
      v[2 * i]     = *(const ushort4*)&support[(size_t)q[i][0] * D_OUT + ch];
      v[2 * i + 1] = *(const ushort4*)&support[(size_t)q[i][2] * D_OUT + ch];
    }
#pragma unroll
    for (int i = 0; i < 4; ++i) {
      const float wa = __int_as_float(q[i][1]);
      const float wb = __int_as_float(q[i][3]);
      a0 = fmaf(wa, bfu2f(v[2 * i].x), a0);
      a1 = fmaf(wa, bfu2f(v[2 * i].y), a1);
      a2 = fmaf(wa, bfu2f(v[2 * i].z), a2);
      a3 = fmaf(wa, bfu2f(v[2 * i].w), a3);
      a0 = fmaf(wb, bfu2f(v[2 * i + 1].x), a0);
      a1 = fmaf(wb, bfu2f(v[2 * i + 1].y), a1);
      a2 = fmaf(wb, bfu2f(v[2 * i + 1].z), a2);
      a3 = fmaf(wb, bfu2f(v[2 * i + 1].w), a3);
    }
  }

  for (; s < d; ++s) {
    const int2  e   = csr[cb + s];
    const float wgt = __int_as_float(e.y);
    const ushort4 v = *(const ushort4*)&support[(size_t)e.x * D_OUT + ch];
    a0 = fmaf(wgt, bfu2f(v.x), a0);
    a1 = fmaf(wgt, bfu2f(v.y), a1);
    a2 = fmaf(wgt, bfu2f(v.z), a2);
    a3 = fmaf(wgt, bfu2f(v.w), a3);
  }

  const float rn = 1.0f / norm[node];
  const float4 b = *(const float4*)&bias[ch];
  float o0 = fmaf(a0, rn, b.x);
  float o1 = fmaf(a1, rn, b.y);
  float o2 = fmaf(a2, rn, b.z);
  float o3 = fmaf(a3, rn, b.w);
  o0 = o0 > 0.f ? o0 : o0 * LEAKY;
  o1 = o1 > 0.f ? o1 : o1 * LEAKY;
  o2 = o2 > 0.f ? o2 : o2 * LEAKY;
  o3 = o3 > 0.f ? o3 : o3 * LEAKY;
  f32x4 ov;
  ov[0] = o0; ov[1] = o1; ov[2] = o2; ov[3] = o3;
  __builtin_nontemporal_store(ov, (f32x4*)&out[(size_t)node * D_OUT + ch]);
}

// ---------------------------------------------------------------------------
// ws layout (bytes):
//   support  bf16  [50000][256]     @ 0          25,600,000
//   Wimg     bf16  32x[256][32] swz @ 25,600,000    524,288
//   csr      int2  [50000][64]      @ 26,124,288 25,600,000
//   deg      int   [50000]          @ 51,724,288    200,000
// ---------------------------------------------------------------------------
extern "C" void kernel_launch(void* const* d_in, const int* in_sizes, int n_in,
                              void* d_out, int out_size, void* d_ws, size_t ws_size,
                              hipStream_t stream) {
  const float* x    = (const float*)d_in[0];
  const float* w    = (const float*)d_in[1];
  const float* bias = (const float*)d_in[2];
  const int*   ei   = (const int*)d_in[3];
  const float* ew   = (const float*)d_in[4];
  const float* norm = (const float*)d_in[5];
  float* out = (float*)d_out;

  char* ws = (char*)d_ws;
  u16*   support = (u16*)  (ws);
  char*  img     =         (ws + 25600000);
  int2*  csr     = (int2*) (ws + 26124288);
  int*   deg     = (int*)  (ws + 51724288);

  wconv_kernel<<<128, 256, 0, stream>>>(w, img, deg);
  gemm_build_kernel<<<BUILD_BLOCKS + GEMM_BLOCKS, 512, 0, stream>>>(
      x, img, support, ei, ew, deg, csr);
  agg_kernel<<<N_NODES / 4, 256, 0, stream>>>(support, deg, csr, norm, bias, out);
}